// Round 9
// baseline (115.917 us; speedup 1.0000x reference)
//
#include <hip/hip_runtime.h>
#include <hip/hip_bf16.h>

#define DIM 256
#define NP 2048
#define NH 8
#define BATCH 2
#define DH 32

typedef __attribute__((ext_vector_type(8))) short bshort8;
typedef __attribute__((ext_vector_type(4))) short bshort4;
typedef __attribute__((ext_vector_type(4))) float f32x4;

#define LOG2E 1.44269504f
// (Dh^-0.5) * log2(e), folded into WT rows 0..255 (W_q) at prep time
#define QSCALE (0.17677669529663687f * LOG2E)

union U16B { uint4 u; bshort8 s8; __hip_bfloat16 h[8]; };
union U8B  { uint2 u; bshort4 s4; __hip_bfloat16 h[4]; };

__device__ __forceinline__ float fexp2(float x) { return __builtin_amdgcn_exp2f(x); }
// pack two fp32 -> two bf16 (truncation) in one v_perm
__device__ __forceinline__ unsigned packbf(float hi, float lo) {
    return __builtin_amdgcn_perm(__float_as_uint(hi), __float_as_uint(lo), 0x07060302u);
}

// LDS tile addressing: 64 rows x 256 elems, XOR-swizzled 16B granules.
__device__ __forceinline__ int lds_addr(int row, int colg) {
    return row * 256 + (((colg ^ (row & 7)) & 31) << 3);
}

// ============ kernel 0: prep — W transpose -> bf16 WT[1024][256] ============
// WT rows: 0-255 Wq^T*QSCALE, 256-511 Wk^T, 512-767 Wv^T, 768-1023 Wproj^T
__global__ __launch_bounds__(256) void prep_kernel(
    const float* __restrict__ Wqk,
    const float* __restrict__ Wv,
    const float* __restrict__ Wproj,
    __hip_bfloat16* __restrict__ WT) {
    const int t = threadIdx.x;
    const int blk = blockIdx.x;
    __shared__ float ts[64][65];
    const int ct = blk >> 2, k0 = (blk & 3) * 64;
    const int c0 = ct * 64;
    const float* src; int ldw, cs0; float scl = 1.0f;
    if (ct < 8)       { src = Wqk;   ldw = 512; cs0 = c0;      if (ct < 4) scl = QSCALE; }
    else if (ct < 12) { src = Wv;    ldw = 256; cs0 = c0 - 512; }
    else              { src = Wproj; ldw = 256; cs0 = c0 - 768; }
    const int cc = t & 63, tq = t >> 6;
#pragma unroll
    for (int j = 0; j < 16; j++) {
        int kk = tq * 16 + j;
        ts[kk][cc] = src[(size_t)(k0 + kk) * ldw + cs0 + cc];
    }
    __syncthreads();
    const int kk2 = t & 63;
#pragma unroll
    for (int j = 0; j < 16; j++) {
        int cc2 = tq * 16 + j;
        WT[(size_t)(c0 + cc2) * 256 + k0 + kk2] = __float2bfloat16(ts[kk2][cc2] * scl);
    }
}

// ============ kernel 1: QKV projection — LDS-tiled bf16 MFMA GEMM ===========
// A = x[4096x256] fp32 (converted during staging), B = WT rows 0..767.
// grid (64,12), 256 thr. Outputs: q,k in [bh][n][32] (coalesced via LDS
// transpose); v in frag layout vF[bh][kt][vh][lane][4] (direct contiguous).
__global__ __launch_bounds__(256) void qkv_mfma(
    const float* __restrict__ x,
    const __hip_bfloat16* __restrict__ WT,
    __hip_bfloat16* __restrict__ q,
    __hip_bfloat16* __restrict__ k,
    __hip_bfloat16* __restrict__ vF) {
    __shared__ __align__(16) __hip_bfloat16 As[64 * 256];
    __shared__ __align__(16) __hip_bfloat16 Bs[64 * 256];
    const int t = threadIdx.x, lane = t & 63, wvid = t >> 6;
    const int l15 = lane & 15, l4 = lane >> 4;
    const int m0 = blockIdx.x * 64;
    const int nb0 = blockIdx.y * 64;

#pragma unroll
    for (int j = 0; j < 8; j++) {
        const int flat = j * 2048 + t * 8;
        const int row = flat >> 8, colg = (flat >> 3) & 31;
        float4 f0 = *(const float4*)(x + (size_t)m0 * 256 + flat);
        float4 f1 = *(const float4*)(x + (size_t)m0 * 256 + flat + 4);
        U16B a;
        a.h[0] = __float2bfloat16(f0.x); a.h[1] = __float2bfloat16(f0.y);
        a.h[2] = __float2bfloat16(f0.z); a.h[3] = __float2bfloat16(f0.w);
        a.h[4] = __float2bfloat16(f1.x); a.h[5] = __float2bfloat16(f1.y);
        a.h[6] = __float2bfloat16(f1.z); a.h[7] = __float2bfloat16(f1.w);
        *(uint4*)&As[lds_addr(row, colg)] = a.u;
        *(uint4*)&Bs[lds_addr(row, colg)] = *(const uint4*)(WT + (size_t)nb0 * 256 + flat);
    }
    __syncthreads();

    f32x4 acc[4] = {{0.f,0.f,0.f,0.f},{0.f,0.f,0.f,0.f},{0.f,0.f,0.f,0.f},{0.f,0.f,0.f,0.f}};
#pragma unroll
    for (int kk = 0; kk < 8; kk++) {
        const int colg = kk * 4 + l4;
        U16B bw; bw.u = *(const uint4*)&Bs[lds_addr(wvid * 16 + l15, colg)];
#pragma unroll
        for (int mt = 0; mt < 4; mt++) {
            U16B ax; ax.u = *(const uint4*)&As[lds_addr(mt * 16 + l15, colg)];
            acc[mt] = __builtin_amdgcn_mfma_f32_16x16x32_bf16(ax.s8, bw.s8, acc[mt], 0, 0, 0);
        }
    }

    if (nb0 < 512) {
        // q/k: transpose 64x64 C-tile through LDS -> coalesced 32B stores
        __syncthreads();                       // all As/Bs reads done
        __hip_bfloat16* Tr = As;               // 64 rows x stride 72
#pragma unroll
        for (int mt = 0; mt < 4; mt++)
#pragma unroll
            for (int r = 0; r < 4; r++)
                Tr[(mt * 16 + l4 * 4 + r) * 72 + wvid * 16 + l15] = __float2bfloat16(acc[mt][r]);
        __syncthreads();
        const int hh = t >> 7, row = (t >> 1) & 63, part = t & 1;
        const bool isq = (nb0 < 256);
        const int cc = (isq ? nb0 : nb0 - 256) + hh * 32;   // 32-aligned col base
        const int hOut = cc >> 5;
        const int tok = m0 + row;
        const int b = tok >> 11, n = tok & (NP - 1);
        __hip_bfloat16* dst = (isq ? q : k) + ((size_t)(b * NH + hOut) * NP + n) * DH + part * 16;
        uint4 w0 = *(const uint4*)&Tr[row * 72 + hh * 32 + part * 16];
        uint4 w1 = *(const uint4*)&Tr[row * 72 + hh * 32 + part * 16 + 8];
        *(uint4*)dst = w0;
        *(uint4*)(dst + 8) = w1;
    } else {
        // v -> frag layout: per (mt): contiguous 8B/lane store (lane'=lane, j=r)
        const int cbase = (nb0 - 512) + wvid * 16;        // wave-uniform
        const int h = cbase >> 5;
        const int vh = (cbase >> 4) & 1;
        const int b = m0 >> 11;
#pragma unroll
        for (int mt = 0; mt < 4; mt++) {
            const int kt = ((m0 & (NP - 1)) >> 4) + mt;
            U8B vv;
#pragma unroll
            for (int r = 0; r < 4; r++) vv.h[r] = __float2bfloat16(acc[mt][r]);
            *(uint2*)(vF + ((((size_t)((b * NH + h) * 128 + kt)) * 2 + vh) * 64 + lane) * 4) = vv.u;
        }
    }
}

// ============ kernel 2: attention — no K/V LDS, no K-loop barriers ==========
// grid 512 = bh(16) x qb(32 of 64q). 512 thr / 8 waves: qt = wv&3, kh = wv>>2.
// K frags: [bh][key][32] -> contiguous 1KB/wave. V frags: vF layout -> 512B.
__global__ __launch_bounds__(512, 4) void attn_kernel(
    const __hip_bfloat16* __restrict__ qg,
    const __hip_bfloat16* __restrict__ kg,
    const __hip_bfloat16* __restrict__ vF,
    const float* __restrict__ Wpos,
    const float* __restrict__ bpos,
    const float* __restrict__ gating,
    __hip_bfloat16* __restrict__ ao) {
    __shared__ float cmb[4][2][32][16];   // [qt][type][d][q] upper-half partial O
    __shared__ float cls[4][2][16];       // [qt][type][q]    upper-half partial sums

    const int t = threadIdx.x;
    const int lane = t & 63, wvid = t >> 6;
    const int l15 = lane & 15, l4 = lane >> 4;
    const int qt = wvid & 3, kh = wvid >> 2;
    const int bh = blockIdx.x >> 5, qb = blockIdx.x & 31;
    const int h = bh & (NH - 1), b = bh >> 3;
    const int q0 = qb * 64 + qt * 16;
    const int myq = q0 + l15;

    const float w0 = Wpos[h] * LOG2E;
    const float w1 = Wpos[NH + h] * LOG2E;
    const float g = 1.0f / (1.0f + __expf(-gating[h]));
    const float nf = (float)myq;
    const float pmax = fmaxf(0.f, fmaxf((w0 + w1) * nf, (w1 - w0) * (2047.0f - nf)));
    const float npmax = -pmax;
    const float rA = fexp2(-(w0 + w1));
    const float rB = fexp2(w1 - w0);

    U16B qv;
    qv.u = *(const uint4*)(qg + ((size_t)bh * NP + myq) * DH + l4 * 8);

    const __hip_bfloat16* kbase = kg + (size_t)bh * NP * DH;
    const __hip_bfloat16* vbase = vF + (size_t)bh * 128 * 2 * 256;
    const int kstart = kh * 1024;

    f32x4 os0 = {0.f,0.f,0.f,0.f}, os1 = {0.f,0.f,0.f,0.f};
    f32x4 op0 = {0.f,0.f,0.f,0.f}, op1 = {0.f,0.f,0.f,0.f};
    float ls = 0.f, lp = 0.f;

#pragma unroll 2
    for (int it = 0; it < 16; ++it) {
        const int kb0 = kstart + it * 64;
        const int kt0 = kb0 >> 4;

        // coalesced frag loads (L1-shared across the 4 qt waves)
        U8B vfr[8];
#pragma unroll
        for (int ktl = 0; ktl < 4; ktl++)
#pragma unroll
            for (int vh = 0; vh < 2; vh++)
                vfr[vh * 4 + ktl].u = *(const uint2*)(vbase +
                    (((size_t)(kt0 + ktl) * 2 + vh) * 64 + lane) * 4);
        U16B kf[4];
#pragma unroll
        for (int kt = 0; kt < 4; kt++)
            kf[kt].u = *(const uint4*)(kbase + (size_t)(kb0 + kt * 16 + l15) * DH + l4 * 8);

        // S^T = K@Q^T: D[key=l4*4+r][query=l15]
        f32x4 st4[4];
#pragma unroll
        for (int kt = 0; kt < 4; kt++)
            st4[kt] = __builtin_amdgcn_mfma_f32_16x16x32_bf16(
                kf[kt].s8, qv.s8, (f32x4){0.f,0.f,0.f,0.f}, 0, 0, 0);

        // exp -> pack in registers -> AV MFMAs (16x16x16)
#pragma unroll
        for (int kt = 0; kt < 4; kt++) {
            float es0 = fexp2(st4[kt][0]), es1 = fexp2(st4[kt][1]);
            float es2 = fexp2(st4[kt][2]), es3 = fexp2(st4[kt][3]);
            ls += (es0 + es1) + (es2 + es3);
            const float d0 = nf - (float)(kb0 + kt * 16 + l4 * 4);
            float ep0 = fexp2(fmaf(w1, fabsf(d0), fmaf(w0, d0, npmax)));
            float ep1 = ep0 * ((d0 >= 1.f) ? rA : rB);
            float ep2 = ep1 * ((d0 >= 2.f) ? rA : rB);
            float ep3 = ep2 * ((d0 >= 3.f) ? rA : rB);
            lp += (ep0 + ep1) + (ep2 + ep3);
            U8B pc, pp;
            pc.u.x = packbf(es1, es0); pc.u.y = packbf(es3, es2);
            pp.u.x = packbf(ep1, ep0); pp.u.y = packbf(ep3, ep2);
            os0 = __builtin_amdgcn_mfma_f32_16x16x16bf16_1k(vfr[kt].s4,     pc.s4, os0, 0, 0, 0);
            os1 = __builtin_amdgcn_mfma_f32_16x16x16bf16_1k(vfr[4 + kt].s4, pc.s4, os1, 0, 0, 0);
            op0 = __builtin_amdgcn_mfma_f32_16x16x16bf16_1k(vfr[kt].s4,     pp.s4, op0, 0, 0, 0);
            op1 = __builtin_amdgcn_mfma_f32_16x16x16bf16_1k(vfr[4 + kt].s4, pp.s4, op1, 0, 0, 0);
        }
    }

    ls += __shfl_xor(ls, 16, 64); ls += __shfl_xor(ls, 32, 64);
    lp += __shfl_xor(lp, 16, 64); lp += __shfl_xor(lp, 32, 64);

    if (kh == 1) {
#pragma unroll
        for (int r = 0; r < 4; r++) {
            cmb[qt][0][l4 * 4 + r][l15]      = os0[r];
            cmb[qt][0][16 + l4 * 4 + r][l15] = os1[r];
            cmb[qt][1][l4 * 4 + r][l15]      = op0[r];
            cmb[qt][1][16 + l4 * 4 + r][l15] = op1[r];
        }
        if (l4 == 0) { cls[qt][0][l15] = ls; cls[qt][1][l15] = lp; }
    }
    __syncthreads();
    if (kh == 0) {
        ls += cls[qt][0][l15]; lp += cls[qt][1][l15];
        const float cs = (1.0f - g) / ls;
        const float cp = g / lp;
        const size_t orow = ((size_t)b * NP + myq) * DIM + h * DH;
        U8B o0, o1;
#pragma unroll
        for (int r = 0; r < 4; r++) {
            o0.h[r] = __float2bfloat16(cs * (os0[r] + cmb[qt][0][l4 * 4 + r][l15]) +
                                       cp * (op0[r] + cmb[qt][1][l4 * 4 + r][l15]));
            o1.h[r] = __float2bfloat16(cs * (os1[r] + cmb[qt][0][16 + l4 * 4 + r][l15]) +
                                       cp * (op1[r] + cmb[qt][1][16 + l4 * 4 + r][l15]));
        }
        *(uint2*)(ao + orow + l4 * 4)      = o0.u;
        *(uint2*)(ao + orow + 16 + l4 * 4) = o1.u;
    }
}

// ============ kernel 3: output projection — LDS-tiled bf16 MFMA GEMM ========
__global__ __launch_bounds__(256) void proj_mfma(
    const __hip_bfloat16* __restrict__ ao,
    const __hip_bfloat16* __restrict__ WT,
    const float* __restrict__ bias,
    float* __restrict__ out) {
    __shared__ __align__(16) __hip_bfloat16 As[64 * 256];
    __shared__ __align__(16) __hip_bfloat16 Bs[64 * 256];
    const int t = threadIdx.x, lane = t & 63, wvid = t >> 6;
    const int l15 = lane & 15, l4 = lane >> 4;
    const int m0 = blockIdx.x * 64;
    const int nb0 = blockIdx.y * 64;
    const int nc = nb0 + wvid * 16 + l15;

#pragma unroll
    for (int j = 0; j < 8; j++) {
        const int flat = j * 2048 + t * 8;
        const int row = flat >> 8, colg = (flat >> 3) & 31;
        *(uint4*)&As[lds_addr(row, colg)] = *(const uint4*)(ao + (size_t)m0 * 256 + flat);
        *(uint4*)&Bs[lds_addr(row, colg)] = *(const uint4*)(WT + (size_t)(768 + nb0) * 256 + flat);
    }
    __syncthreads();

    f32x4 acc[4] = {{0.f,0.f,0.f,0.f},{0.f,0.f,0.f,0.f},{0.f,0.f,0.f,0.f},{0.f,0.f,0.f,0.f}};
#pragma unroll
    for (int kk = 0; kk < 8; kk++) {
        const int colg = kk * 4 + l4;
        U16B bw; bw.u = *(const uint4*)&Bs[lds_addr(wvid * 16 + l15, colg)];
#pragma unroll
        for (int mt = 0; mt < 4; mt++) {
            U16B ax; ax.u = *(const uint4*)&As[lds_addr(mt * 16 + l15, colg)];
            acc[mt] = __builtin_amdgcn_mfma_f32_16x16x32_bf16(ax.s8, bw.s8, acc[mt], 0, 0, 0);
        }
    }

    const float bb = bias[nc];
#pragma unroll
    for (int mt = 0; mt < 4; mt++)
#pragma unroll
        for (int r = 0; r < 4; r++) {
            int tok = m0 + mt * 16 + l4 * 4 + r;
            out[(size_t)tok * 256 + nc] = acc[mt][r] + bb;
        }
}

extern "C" void kernel_launch(void* const* d_in, const int* in_sizes, int n_in,
                              void* d_out, int out_size, void* d_ws, size_t ws_size,
                              hipStream_t stream) {
    const float* x      = (const float*)d_in[0];
    const float* Wqk    = (const float*)d_in[1];
    const float* Wv     = (const float*)d_in[2];
    const float* Wproj  = (const float*)d_in[3];
    const float* bproj  = (const float*)d_in[4];
    const float* Wpos   = (const float*)d_in[5];
    const float* bpos   = (const float*)d_in[6];
    const float* gating = (const float*)d_in[7];
    float* out = (float*)d_out;

    const size_t nElem = (size_t)BATCH * NP * DIM;  // 1,048,576
    char* w = (char*)d_ws;
    __hip_bfloat16* WT = (__hip_bfloat16*)w;        // 512KB
    __hip_bfloat16* q  = WT + 262144;
    __hip_bfloat16* k  = q + nElem;
    __hip_bfloat16* vF = k + nElem;                 // frag layout
    __hip_bfloat16* ao = vF + nElem;                // total 8.5MB

    prep_kernel<<<64, 256, 0, stream>>>(Wqk, Wv, Wproj, WT);
    qkv_mfma<<<dim3(64, 12), 256, 0, stream>>>(x, WT, q, k, vF);
    attn_kernel<<<BATCH * NH * (NP / 64), 512, 0, stream>>>(q, k, vF, Wpos, bpos, gating, ao);
    proj_mfma<<<dim3(64, 4), 256, 0, stream>>>(ao, WT, bproj, out);
}

// Round 10
// 109.080 us; speedup vs baseline: 1.0627x; 1.0627x over previous
//
#include <hip/hip_runtime.h>
#include <hip/hip_bf16.h>

#define DIM 256
#define NP 2048
#define NH 8
#define BATCH 2
#define DH 32

typedef __attribute__((ext_vector_type(8))) short bshort8;
typedef __attribute__((ext_vector_type(4))) short bshort4;
typedef __attribute__((ext_vector_type(4))) float f32x4;

#define LOG2E 1.44269504f
// (Dh^-0.5) * log2(e), folded into WT rows 0..255 (W_q) at prep time
#define QSCALE (0.17677669529663687f * LOG2E)

union U16B { uint4 u; bshort8 s8; __hip_bfloat16 h[8]; };
union U8B  { uint2 u; bshort4 s4; __hip_bfloat16 h[4]; };

__device__ __forceinline__ float fexp2(float x) { return __builtin_amdgcn_exp2f(x); }
// pack two fp32 -> two bf16 (truncation) in one v_perm
__device__ __forceinline__ unsigned packbf(float hi, float lo) {
    return __builtin_amdgcn_perm(__float_as_uint(hi), __float_as_uint(lo), 0x07060302u);
}

// LDS tile addressing: 64 rows x 256 elems, XOR-swizzled 16B granules.
__device__ __forceinline__ int lds_addr(int row, int colg) {
    return row * 256 + (((colg ^ (row & 7)) & 31) << 3);
}

// ============ kernel 0: prep — W transpose -> bf16 WT[1024][256] ============
// WT rows: 0-255 Wq^T*QSCALE, 256-511 Wk^T, 512-767 Wv^T, 768-1023 Wproj^T
__global__ __launch_bounds__(256) void prep_kernel(
    const float* __restrict__ Wqk,
    const float* __restrict__ Wv,
    const float* __restrict__ Wproj,
    __hip_bfloat16* __restrict__ WT) {
    const int t = threadIdx.x;
    const int blk = blockIdx.x;
    __shared__ float ts[64][65];
    const int ct = blk >> 2, k0 = (blk & 3) * 64;
    const int c0 = ct * 64;
    const float* src; int ldw, cs0; float scl = 1.0f;
    if (ct < 8)       { src = Wqk;   ldw = 512; cs0 = c0;      if (ct < 4) scl = QSCALE; }
    else if (ct < 12) { src = Wv;    ldw = 256; cs0 = c0 - 512; }
    else              { src = Wproj; ldw = 256; cs0 = c0 - 768; }
    const int cc = t & 63, tq = t >> 6;
#pragma unroll
    for (int j = 0; j < 16; j++) {
        int kk = tq * 16 + j;
        ts[kk][cc] = src[(size_t)(k0 + kk) * ldw + cs0 + cc];
    }
    __syncthreads();
    const int kk2 = t & 63;
#pragma unroll
    for (int j = 0; j < 16; j++) {
        int cc2 = tq * 16 + j;
        WT[(size_t)(c0 + cc2) * 256 + k0 + kk2] = __float2bfloat16(ts[kk2][cc2] * scl);
    }
}

// ============ kernel 1: QKV projection — LDS-tiled bf16 MFMA GEMM ===========
// A = x[4096x256] fp32 (converted during staging), B = WT rows 0..767.
// Outputs: q,k in [bh][n][32] (coalesced via LDS transpose); v in frag layout
// vF[bh][kt][vh][lane][4] (direct contiguous stores).
__global__ __launch_bounds__(256) void qkv_mfma(
    const float* __restrict__ x,
    const __hip_bfloat16* __restrict__ WT,
    __hip_bfloat16* __restrict__ q,
    __hip_bfloat16* __restrict__ k,
    __hip_bfloat16* __restrict__ vF) {
    __shared__ __align__(16) __hip_bfloat16 As[64 * 256];
    __shared__ __align__(16) __hip_bfloat16 Bs[64 * 256];
    const int t = threadIdx.x, lane = t & 63, wvid = t >> 6;
    const int l15 = lane & 15, l4 = lane >> 4;
    const int m0 = blockIdx.x * 64;
    const int nb0 = blockIdx.y * 64;

#pragma unroll
    for (int j = 0; j < 8; j++) {
        const int flat = j * 2048 + t * 8;
        const int row = flat >> 8, colg = (flat >> 3) & 31;
        float4 f0 = *(const float4*)(x + (size_t)m0 * 256 + flat);
        float4 f1 = *(const float4*)(x + (size_t)m0 * 256 + flat + 4);
        U16B a;
        a.h[0] = __float2bfloat16(f0.x); a.h[1] = __float2bfloat16(f0.y);
        a.h[2] = __float2bfloat16(f0.z); a.h[3] = __float2bfloat16(f0.w);
        a.h[4] = __float2bfloat16(f1.x); a.h[5] = __float2bfloat16(f1.y);
        a.h[6] = __float2bfloat16(f1.z); a.h[7] = __float2bfloat16(f1.w);
        *(uint4*)&As[lds_addr(row, colg)] = a.u;
        *(uint4*)&Bs[lds_addr(row, colg)] = *(const uint4*)(WT + (size_t)nb0 * 256 + flat);
    }
    __syncthreads();

    f32x4 acc[4] = {{0.f,0.f,0.f,0.f},{0.f,0.f,0.f,0.f},{0.f,0.f,0.f,0.f},{0.f,0.f,0.f,0.f}};
#pragma unroll
    for (int kk = 0; kk < 8; kk++) {
        const int colg = kk * 4 + l4;
        U16B bw; bw.u = *(const uint4*)&Bs[lds_addr(wvid * 16 + l15, colg)];
#pragma unroll
        for (int mt = 0; mt < 4; mt++) {
            U16B ax; ax.u = *(const uint4*)&As[lds_addr(mt * 16 + l15, colg)];
            acc[mt] = __builtin_amdgcn_mfma_f32_16x16x32_bf16(ax.s8, bw.s8, acc[mt], 0, 0, 0);
        }
    }

    if (nb0 < 512) {
        // q/k: transpose 64x64 C-tile through LDS -> coalesced 32B stores
        __syncthreads();                       // all As/Bs reads done
        __hip_bfloat16* Tr = As;               // 64 rows x stride 72
#pragma unroll
        for (int mt = 0; mt < 4; mt++)
#pragma unroll
            for (int r = 0; r < 4; r++)
                Tr[(mt * 16 + l4 * 4 + r) * 72 + wvid * 16 + l15] = __float2bfloat16(acc[mt][r]);
        __syncthreads();
        const int hh = t >> 7, row = (t >> 1) & 63, part = t & 1;
        const bool isq = (nb0 < 256);
        const int cc = (isq ? nb0 : nb0 - 256) + hh * 32;   // 32-aligned col base
        const int hOut = cc >> 5;
        const int tok = m0 + row;
        const int b = tok >> 11, n = tok & (NP - 1);
        __hip_bfloat16* dst = (isq ? q : k) + ((size_t)(b * NH + hOut) * NP + n) * DH + part * 16;
        uint4 w0 = *(const uint4*)&Tr[row * 72 + hh * 32 + part * 16];
        uint4 w1 = *(const uint4*)&Tr[row * 72 + hh * 32 + part * 16 + 8];
        *(uint4*)dst = w0;
        *(uint4*)(dst + 8) = w1;
    } else {
        // v -> frag layout: per (mt): contiguous 8B/lane store (lane'=lane, j=r)
        const int cbase = (nb0 - 512) + wvid * 16;        // wave-uniform
        const int h = cbase >> 5;
        const int vh = (cbase >> 4) & 1;
        const int b = m0 >> 11;
#pragma unroll
        for (int mt = 0; mt < 4; mt++) {
            const int kt = ((m0 & (NP - 1)) >> 4) + mt;
            U8B vv;
#pragma unroll
            for (int r = 0; r < 4; r++) vv.h[r] = __float2bfloat16(acc[mt][r]);
            *(uint2*)(vF + ((((size_t)((b * NH + h) * 128 + kt)) * 2 + vh) * 64 + lane) * 4) = vv.u;
        }
    }
}

// ============ kernel 2: attention — dbuf LDS staging, frag-native V =========
// grid 512 = bh(16) x qb(32 of 64q). 512 thr / 8 waves: qt = wv&3, kh = wv>>2.
__global__ __launch_bounds__(512, 4) void attn_kernel(
    const __hip_bfloat16* __restrict__ qg,
    const __hip_bfloat16* __restrict__ kg,
    const __hip_bfloat16* __restrict__ vF,
    const float* __restrict__ Wpos,
    const float* __restrict__ bpos,
    const float* __restrict__ gating,
    __hip_bfloat16* __restrict__ ao) {
    __shared__ __align__(16) __hip_bfloat16 Kt[2][2][64][40];  // [kh][buf][key][dh pad40]
    __shared__ __align__(16) __hip_bfloat16 Vf[2][2][2048];    // [kh][buf] frag-native flat
    __shared__ float cmb[4][2][32][16];   // [qt][type][d][q] upper-half partial O
    __shared__ float cls[4][2][16];       // [qt][type][q]    upper-half partial sums

    const int t = threadIdx.x;
    const int lane = t & 63, wvid = t >> 6;
    const int l15 = lane & 15, l4 = lane >> 4;
    const int qt = wvid & 3, kh = wvid >> 2;
    const int bh = blockIdx.x >> 5, qb = blockIdx.x & 31;
    const int h = bh & (NH - 1), b = bh >> 3;
    const int q0 = qb * 64 + qt * 16;
    const int myq = q0 + l15;

    // staging role (same half as this thread's wave: t>>8 == kh)
    const int st_ = t & 255;
    const int kstart = kh * 1024;
    const __hip_bfloat16* kptr = kg + (size_t)bh * NP * DH + (size_t)(kstart + (st_ >> 2)) * DH + (st_ & 3) * 8;
    const __hip_bfloat16* vptr = vF + (size_t)bh * 65536 + (size_t)kstart * 32 + st_ * 8;

    uint4 kreg = *(const uint4*)kptr;
    uint4 vreg = *(const uint4*)vptr;
    *(uint4*)&Kt[kh][0][st_ >> 2][(st_ & 3) * 8] = kreg;
    *(uint4*)&Vf[kh][0][st_ * 8] = vreg;

    const float w0 = Wpos[h] * LOG2E;
    const float w1 = Wpos[NH + h] * LOG2E;
    const float g = 1.0f / (1.0f + __expf(-gating[h]));
    const float nf = (float)myq;
    const float pmax = fmaxf(0.f, fmaxf((w0 + w1) * nf, (w1 - w0) * (2047.0f - nf)));
    const float npmax = -pmax;
    const float rA = fexp2(-(w0 + w1));
    const float rB = fexp2(w1 - w0);

    U16B qv;
    qv.u = *(const uint4*)(qg + ((size_t)bh * NP + myq) * DH + l4 * 8);

    __syncthreads();

    f32x4 os0 = {0.f,0.f,0.f,0.f}, os1 = {0.f,0.f,0.f,0.f};
    f32x4 op0 = {0.f,0.f,0.f,0.f}, op1 = {0.f,0.f,0.f,0.f};
    float ls = 0.f, lp = 0.f;

    for (int it = 0; it < 16; ++it) {
        const int cur = it & 1, nxt = cur ^ 1;

        // prefetch next tile into registers (coalesced; V is a flat 4KB copy)
        if (it < 15) {
            kreg = *(const uint4*)(kptr + (size_t)(it + 1) * 64 * DH);
            vreg = *(const uint4*)(vptr + (size_t)(it + 1) * 2048);
        }

        // S^T = K@Q^T: A-frag from LDS K-tile -> D[key=l4*4+r][query=l15]
        f32x4 st4[4];
#pragma unroll
        for (int kt = 0; kt < 4; kt++) {
            U16B kf; kf.u = *(const uint4*)&Kt[kh][cur][kt * 16 + l15][l4 * 8];
            st4[kt] = __builtin_amdgcn_mfma_f32_16x16x32_bf16(
                kf.s8, qv.s8, (f32x4){0.f,0.f,0.f,0.f}, 0, 0, 0);
        }

        // V^T A-frags (16x16x16) from frag-native LDS (conflict-free 8B/lane)
        U8B vfr[8];
#pragma unroll
        for (int vh = 0; vh < 2; vh++)
#pragma unroll
            for (int ktl = 0; ktl < 4; ktl++)
                vfr[vh * 4 + ktl].u = *(const uint2*)&Vf[kh][cur][((ktl * 2 + vh) * 64 + lane) * 4];

        // exp -> pack in registers -> AV MFMAs
        const int kb0 = kstart + it * 64;
#pragma unroll
        for (int kt = 0; kt < 4; kt++) {
            float es0 = fexp2(st4[kt][0]), es1 = fexp2(st4[kt][1]);
            float es2 = fexp2(st4[kt][2]), es3 = fexp2(st4[kt][3]);
            ls += (es0 + es1) + (es2 + es3);
            const float d0 = nf - (float)(kb0 + kt * 16 + l4 * 4);
            float ep0 = fexp2(fmaf(w1, fabsf(d0), fmaf(w0, d0, npmax)));
            float ep1 = ep0 * ((d0 >= 1.f) ? rA : rB);
            float ep2 = ep1 * ((d0 >= 2.f) ? rA : rB);
            float ep3 = ep2 * ((d0 >= 3.f) ? rA : rB);
            lp += (ep0 + ep1) + (ep2 + ep3);
            U8B pc, pp;
            pc.u.x = packbf(es1, es0); pc.u.y = packbf(es3, es2);
            pp.u.x = packbf(ep1, ep0); pp.u.y = packbf(ep3, ep2);
            os0 = __builtin_amdgcn_mfma_f32_16x16x16bf16_1k(vfr[kt].s4,     pc.s4, os0, 0, 0, 0);
            os1 = __builtin_amdgcn_mfma_f32_16x16x16bf16_1k(vfr[4 + kt].s4, pc.s4, os1, 0, 0, 0);
            op0 = __builtin_amdgcn_mfma_f32_16x16x16bf16_1k(vfr[kt].s4,     pp.s4, op0, 0, 0, 0);
            op1 = __builtin_amdgcn_mfma_f32_16x16x16bf16_1k(vfr[4 + kt].s4, pp.s4, op1, 0, 0, 0);
        }

        // stage next tile to LDS
        if (it < 15) {
            *(uint4*)&Kt[kh][nxt][st_ >> 2][(st_ & 3) * 8] = kreg;
            *(uint4*)&Vf[kh][nxt][st_ * 8] = vreg;
        }
        __syncthreads();
    }

    ls += __shfl_xor(ls, 16, 64); ls += __shfl_xor(ls, 32, 64);
    lp += __shfl_xor(lp, 16, 64); lp += __shfl_xor(lp, 32, 64);

    if (kh == 1) {
#pragma unroll
        for (int r = 0; r < 4; r++) {
            cmb[qt][0][l4 * 4 + r][l15]      = os0[r];
            cmb[qt][0][16 + l4 * 4 + r][l15] = os1[r];
            cmb[qt][1][l4 * 4 + r][l15]      = op0[r];
            cmb[qt][1][16 + l4 * 4 + r][l15] = op1[r];
        }
        if (l4 == 0) { cls[qt][0][l15] = ls; cls[qt][1][l15] = lp; }
    }
    __syncthreads();
    if (kh == 0) {
        ls += cls[qt][0][l15]; lp += cls[qt][1][l15];
        const float cs = (1.0f - g) / ls;
        const float cp = g / lp;
        const size_t orow = ((size_t)b * NP + myq) * DIM + h * DH;
        U8B o0, o1;
#pragma unroll
        for (int r = 0; r < 4; r++) {
            o0.h[r] = __float2bfloat16(cs * (os0[r] + cmb[qt][0][l4 * 4 + r][l15]) +
                                       cp * (op0[r] + cmb[qt][1][l4 * 4 + r][l15]));
            o1.h[r] = __float2bfloat16(cs * (os1[r] + cmb[qt][0][16 + l4 * 4 + r][l15]) +
                                       cp * (op1[r] + cmb[qt][1][16 + l4 * 4 + r][l15]));
        }
        *(uint2*)(ao + orow + l4 * 4)      = o0.u;
        *(uint2*)(ao + orow + 16 + l4 * 4) = o1.u;
    }
}

// ============ kernel 3: output projection — LDS-tiled bf16 MFMA GEMM ========
// fp32 epilogue transposed through LDS for fully-coalesced 16B stores.
__global__ __launch_bounds__(256) void proj_mfma(
    const __hip_bfloat16* __restrict__ ao,
    const __hip_bfloat16* __restrict__ WT,
    const float* __restrict__ bias,
    float* __restrict__ out) {
    __shared__ __align__(16) __hip_bfloat16 As[64 * 256];
    __shared__ __align__(16) __hip_bfloat16 Bs[64 * 256];
    const int t = threadIdx.x, lane = t & 63, wvid = t >> 6;
    const int l15 = lane & 15, l4 = lane >> 4;
    const int m0 = blockIdx.x * 64;
    const int nb0 = blockIdx.y * 64;
    const int nc = nb0 + wvid * 16 + l15;

#pragma unroll
    for (int j = 0; j < 8; j++) {
        const int flat = j * 2048 + t * 8;
        const int row = flat >> 8, colg = (flat >> 3) & 31;
        *(uint4*)&As[lds_addr(row, colg)] = *(const uint4*)(ao + (size_t)m0 * 256 + flat);
        *(uint4*)&Bs[lds_addr(row, colg)] = *(const uint4*)(WT + (size_t)(768 + nb0) * 256 + flat);
    }
    __syncthreads();

    f32x4 acc[4] = {{0.f,0.f,0.f,0.f},{0.f,0.f,0.f,0.f},{0.f,0.f,0.f,0.f},{0.f,0.f,0.f,0.f}};
#pragma unroll
    for (int kk = 0; kk < 8; kk++) {
        const int colg = kk * 4 + l4;
        U16B bw; bw.u = *(const uint4*)&Bs[lds_addr(wvid * 16 + l15, colg)];
#pragma unroll
        for (int mt = 0; mt < 4; mt++) {
            U16B ax; ax.u = *(const uint4*)&As[lds_addr(mt * 16 + l15, colg)];
            acc[mt] = __builtin_amdgcn_mfma_f32_16x16x32_bf16(ax.s8, bw.s8, acc[mt], 0, 0, 0);
        }
    }

    // epilogue: C-tile (fp32) -> LDS [row=tok 64][col 64 pad68] -> coalesced
    const float bb = bias[nc];
    __syncthreads();
    float* Trf = (float*)As;   // 64*68*4B = 17.4KB fits in As
#pragma unroll
    for (int mt = 0; mt < 4; mt++)
#pragma unroll
        for (int r = 0; r < 4; r++)
            Trf[(mt * 16 + l4 * 4 + r) * 68 + wvid * 16 + l15] = acc[mt][r] + bb;
    __syncthreads();
    const int row = t >> 2, seg = t & 3;
    float4 v0 = *(const float4*)&Trf[row * 68 + seg * 16];
    float4 v1 = *(const float4*)&Trf[row * 68 + seg * 16 + 4];
    float4 v2 = *(const float4*)&Trf[row * 68 + seg * 16 + 8];
    float4 v3 = *(const float4*)&Trf[row * 68 + seg * 16 + 12];
    float* dst = out + (size_t)(m0 + row) * 256 + nb0 + seg * 16;
    *(float4*)dst = v0;
    *(float4*)(dst + 4) = v1;
    *(float4*)(dst + 8) = v2;
    *(float4*)(dst + 12) = v3;
}

extern "C" void kernel_launch(void* const* d_in, const int* in_sizes, int n_in,
                              void* d_out, int out_size, void* d_ws, size_t ws_size,
                              hipStream_t stream) {
    const float* x      = (const float*)d_in[0];
    const float* Wqk    = (const float*)d_in[1];
    const float* Wv     = (const float*)d_in[2];
    const float* Wproj  = (const float*)d_in[3];
    const float* bproj  = (const float*)d_in[4];
    const float* Wpos   = (const float*)d_in[5];
    const float* bpos   = (const float*)d_in[6];
    const float* gating = (const float*)d_in[7];
    float* out = (float*)d_out;

    const size_t nElem = (size_t)BATCH * NP * DIM;  // 1,048,576
    char* w = (char*)d_ws;
    __hip_bfloat16* WT = (__hip_bfloat16*)w;        // 512KB
    __hip_bfloat16* q  = WT + 262144;
    __hip_bfloat16* k  = q + nElem;
    __hip_bfloat16* vF = k + nElem;                 // frag layout
    __hip_bfloat16* ao = vF + nElem;                // total 8.5MB

    prep_kernel<<<64, 256, 0, stream>>>(Wqk, Wv, Wproj, WT);
    qkv_mfma<<<dim3(64, 12), 256, 0, stream>>>(x, WT, q, k, vF);
    attn_kernel<<<BATCH * NH * (NP / 64), 512, 0, stream>>>(q, k, vF, Wpos, bpos, gating, ao);
    proj_mfma<<<dim3(64, 4), 256, 0, stream>>>(ao, WT, bproj, out);
}